// Round 4
// baseline (4181.565 us; speedup 1.0000x reference)
//
#include <hip/hip_runtime.h>
#include <float.h>
#include <math.h>

// (B,H,N,D) = (2,16,2048,128), causal, additive bias [1,H,N,N], mask all-True.
// ORACLE ROUND: scalar (no-MFMA) flash attention, fp32 compute, with runtime
// dtype sniffing (bf16 vs fp32) and input-order detection. Purpose: bisect the
// systematic 4.05-absmax failure between {MFMA layout} and {harness contract}.
#define B_ 2
#define H_ 16
#define N_ 2048
#define D_ 128

__device__ __forceinline__ float bf2f(unsigned short u) {
    union { unsigned int i; float f; } c; c.i = ((unsigned int)u) << 16; return c.f;
}
__device__ __forceinline__ unsigned short f2bf(float f) {
    union { float f; unsigned int i; } c; c.f = f;
    unsigned int x = c.i;
    x += 0x7fffu + ((x >> 16) & 1u);   // RNE
    return (unsigned short)(x >> 16);
}

// True iff the first 64 u16 words of p all look like bf16 with sane exponent.
// fp32 data reinterpreted as u16 has low-mantissa words with uniform-random
// exponent fields -> fails with overwhelming probability (~1e-22).
__device__ __forceinline__ bool sniff_bf16(const void* p) {
    const unsigned short* u = (const unsigned short*)p;
    int bad = 0;
    #pragma unroll 1
    for (int t = 0; t < 64; ++t) {
        const unsigned short x = u[t];
        const int e = (x >> 7) & 0xFF;           // bf16 exponent field
        if (x != 0 && (e < 90 || e > 140)) bad++; // N(0,1) bf16 stays in range
    }
    return bad == 0;
}

// Block = 256 threads: 64 q rows x 4 d-slice threads. Thread (r, c) owns q row
// i = qblk*64+r and dims {c, c+4, c+8, ..., c+124} (interleaved -> 4 distinct
// LDS banks per unrolled step, 16-lane broadcast per address: conflict-free).
// Partners for the dot-product combine are tid^1, tid^2 (same wave, same row).
__global__ __launch_bounds__(256) void attend_oracle(
    const void* __restrict__ Qp, const void* __restrict__ Kp,
    const void* __restrict__ Vp, const void* __restrict__ Bp,
    void* __restrict__ Op)
{
    const bool qf = sniff_bf16(Qp);   // dtype of q/k/v (and of the output)
    const bool bfl = sniff_bf16(Bp);  // dtype of attn_bias (sniffed separately)

    const int tiles_per_bh = N_ / 64;
    const int bh   = blockIdx.x / tiles_per_bh;
    const int qblk = blockIdx.x % tiles_per_bh;
    const int h    = bh % H_;
    const int tid  = threadIdx.x;
    const int r    = tid >> 2;
    const int c    = tid & 3;
    const int i    = qblk * 64 + r;
    const size_t base = (size_t)bh * N_ * D_;
    const float scale = 0.08838834764831845f;   // 1/sqrt(128)

    __shared__ float sK[32 * 132];   // 32 kv rows x 128 dims, stride 132
    __shared__ float sV[32 * 132];

    auto ldin = [&](const void* p, size_t idx, bool f) -> float {
        return f ? bf2f(((const unsigned short*)p)[idx]) : ((const float*)p)[idx];
    };

    float q[32];
    #pragma unroll
    for (int dd = 0; dd < 32; ++dd)
        q[dd] = ldin(Qp, base + (size_t)i * D_ + (c + dd * 4), qf);

    float o[32];
    #pragma unroll
    for (int dd = 0; dd < 32; ++dd) o[dd] = 0.f;
    float m = -1.0e30f, l = 0.f;

    const int nT = qblk * 2 + 2;   // uniform tile count for the whole block
    for (int t = 0; t < nT; ++t) {
        const int kv0 = t * 32;
        __syncthreads();
        for (int e = tid; e < 32 * 128; e += 256) {
            const int kr = e >> 7, dd = e & 127;
            sK[kr * 132 + dd] = ldin(Kp, base + (size_t)(kv0 + kr) * D_ + dd, qf);
            sV[kr * 132 + dd] = ldin(Vp, base + (size_t)(kv0 + kr) * D_ + dd, qf);
        }
        __syncthreads();

        const int jmax = min(32, i - kv0 + 1);   // causal; uniform across partners
        for (int jj = 0; jj < jmax; ++jj) {
            const int j = kv0 + jj;
            float part = 0.f;
            #pragma unroll
            for (int dd = 0; dd < 32; ++dd)
                part += q[dd] * sK[jj * 132 + c + dd * 4];
            part += __shfl_xor(part, 1);
            part += __shfl_xor(part, 2);         // full 128-dim dot on all 4 partners

            float s = part * scale
                    + ldin(Bp, (size_t)h * N_ * N_ + (size_t)i * N_ + j, bfl);

            const float mn = fmaxf(m, s);
            const float al = expf(fmaxf(m - mn, -80.f));
            const float p  = expf(fmaxf(s - mn, -80.f));
            l = l * al + p;
            #pragma unroll
            for (int dd = 0; dd < 32; ++dd)
                o[dd] = o[dd] * al + p * sV[jj * 132 + c + dd * 4];
            m = mn;
        }
    }

    #pragma unroll
    for (int dd = 0; dd < 32; ++dd) {
        const float val = o[dd] / l;             // l >= exp(0-term) > 0 always
        const size_t idx = base + (size_t)i * D_ + (c + dd * 4);
        if (qf) ((unsigned short*)Op)[idx] = f2bf(val);
        else    ((float*)Op)[idx] = val;
    }
}

extern "C" void kernel_launch(void* const* d_in, const int* in_sizes, int n_in,
                              void* d_out, int out_size, void* d_ws, size_t ws_size,
                              hipStream_t stream) {
    // Expected dict order: q,k,v,mask,attn_bias -> sizes [8.4M,8.4M,8.4M,4096,67M].
    // Robustness: if in_sizes[0] is the big bias array, the harness used
    // alphabetical order (attn_bias,k,mask,q,v) -> remap.
    int iq = 0, ik = 1, iv = 2, ib = 4;
    if (n_in >= 5 && in_sizes[0] > in_sizes[1]) { ib = 0; ik = 1; iq = 3; iv = 4; }

    dim3 grid(B_ * H_ * (N_ / 64));   // 1024 blocks
    attend_oracle<<<grid, 256, 0, stream>>>(d_in[iq], d_in[ik], d_in[iv],
                                            d_in[ib], d_out);
}